// Round 2
// baseline (4079.173 us; speedup 1.0000x reference)
//
#include <hip/hip_runtime.h>

static constexpr int INF = 16;
static constexpr int HID = 64;
static constexpr int NC  = 32;

__device__ __forceinline__ int clampi(int v, int n) {
    return v < 0 ? 0 : (v >= n ? n - 1 : v);
}

// ---- degree histogram: deg[col[e]] += 1 ----
__global__ __launch_bounds__(256) void k_degree(const int* __restrict__ col, int E, int n,
                                                float* __restrict__ deg) {
    int i = blockIdx.x * 256 + threadIdx.x;
    if (i < E) atomicAdd(deg + clampi(col[i], n), 1.0f);
}

// ---- dinv = deg>0 ? rsqrt(deg) : 0  (in place) ----
__global__ __launch_bounds__(256) void k_dinv(float* __restrict__ deg, int n) {
    int i = blockIdx.x * 256 + threadIdx.x;
    if (i < n) {
        float d = deg[i];
        deg[i] = (d > 0.0f) ? rsqrtf(d) : 0.0f;
    }
}

// ---- h = x @ W1   [n,16] x [16,64] ; 4 rows/block, 1 thread per (row,col) ----
__global__ __launch_bounds__(256) void k_xw1(const float* __restrict__ x,
                                             const float* __restrict__ W1,
                                             float* __restrict__ h, int n) {
    __shared__ float Wl[INF * HID];      // 4 KB
    __shared__ float xs[4][INF];
    int t = threadIdx.x;
    for (int i = t; i < INF * HID; i += 256) Wl[i] = W1[i];
    int rowBase = blockIdx.x * 4;
    if (t < 4 * INF) {
        int r = t / INF, k = t % INF;
        int row = rowBase + r;
        xs[r][k] = (row < n) ? x[(long long)row * INF + k] : 0.0f;
    }
    __syncthreads();
    int r = t >> 6, c = t & 63;
    int row = rowBase + r;
    if (row < n) {
        float s = 0.0f;
#pragma unroll
        for (int k = 0; k < INF; ++k) s = fmaf(xs[r][k], Wl[k * HID + c], s);
        h[(long long)row * HID + c] = s;
    }
}

// ---- layer-1 scatter: 16 threads/edge, float4 gather + 4 atomics each ----
__global__ __launch_bounds__(256) void k_scatter64(const int* __restrict__ ei, int E, int n,
                                                   const float* __restrict__ dinv,
                                                   const float* __restrict__ h,
                                                   float* __restrict__ agg) {
    long long gid = (long long)blockIdx.x * 256 + threadIdx.x;
    int e = (int)(gid >> 4);
    if (e >= E) return;
    int sub = (int)(gid & 15);
    int row = clampi(ei[e], n);
    int col = clampi(ei[E + e], n);
    float nrm = dinv[row] * dinv[col];
    float4 v = *reinterpret_cast<const float4*>(h + (long long)row * HID + sub * 4);
    float* dst = agg + (long long)col * HID + sub * 4;
    atomicAdd(dst + 0, v.x * nrm);
    atomicAdd(dst + 1, v.y * nrm);
    atomicAdd(dst + 2, v.z * nrm);
    atomicAdd(dst + 3, v.w * nrm);
}

// ---- h2 = relu(agg + b1) @ W2   [n,64] x [64,32] ; 8 rows/block ----
__global__ __launch_bounds__(256) void k_h2(const float* __restrict__ agg,
                                            const float* __restrict__ W2,
                                            const float* __restrict__ b1,
                                            float* __restrict__ h2, int n) {
    __shared__ float Wl[HID * NC];       // 8 KB
    __shared__ float as[8][HID];         // 2 KB
    int t = threadIdx.x;
    for (int i = t; i < HID * NC; i += 256) Wl[i] = W2[i];
    int rowBase = blockIdx.x * 8;
    for (int i = t; i < 8 * HID; i += 256) {
        int r = i >> 6, k = i & 63;
        int row = rowBase + r;
        float v = (row < n) ? agg[(long long)row * HID + k] + b1[k] : 0.0f;
        as[r][k] = fmaxf(v, 0.0f);
    }
    __syncthreads();
    int r = t >> 5, c = t & 31;
    int row = rowBase + r;
    if (row < n) {
        float s = 0.0f;
#pragma unroll
        for (int k = 0; k < HID; ++k) s = fmaf(as[r][k], Wl[k * NC + c], s);
        h2[(long long)row * NC + c] = s;
    }
}

// ---- out = b2 broadcast (scatter-add lands on top) ----
__global__ __launch_bounds__(256) void k_init_out(float* __restrict__ out,
                                                  const float* __restrict__ b2, long long total) {
    long long i = (long long)blockIdx.x * 256 + threadIdx.x;
    if (i < total) out[i] = b2[i & (NC - 1)];
}

// ---- layer-2 scatter: 8 threads/edge ----
__global__ __launch_bounds__(256) void k_scatter32(const int* __restrict__ ei, int E, int n,
                                                   const float* __restrict__ dinv,
                                                   const float* __restrict__ h2,
                                                   float* __restrict__ out) {
    long long gid = (long long)blockIdx.x * 256 + threadIdx.x;
    int e = (int)(gid >> 3);
    if (e >= E) return;
    int sub = (int)(gid & 7);
    int row = clampi(ei[e], n);
    int col = clampi(ei[E + e], n);
    float nrm = dinv[row] * dinv[col];
    float4 v = *reinterpret_cast<const float4*>(h2 + (long long)row * NC + sub * 4);
    float* dst = out + (long long)col * NC + sub * 4;
    atomicAdd(dst + 0, v.x * nrm);
    atomicAdd(dst + 1, v.y * nrm);
    atomicAdd(dst + 2, v.z * nrm);
    atomicAdd(dst + 3, v.w * nrm);
}

extern "C" void kernel_launch(void* const* d_in, const int* in_sizes, int n_in,
                              void* d_out, int out_size, void* d_ws, size_t ws_size,
                              hipStream_t stream) {
    const float* x  = (const float*)d_in[0];
    const int*   ei = (const int*)d_in[1];   // int64 in reference -> pushed as int32
    const float* W1 = (const float*)d_in[2];
    const float* b1 = (const float*)d_in[3];
    const float* W2 = (const float*)d_in[4];
    const float* b2 = (const float*)d_in[5];
    float* out = (float*)d_out;

    const int n = in_sizes[0] / INF;
    const int E = in_sizes[1] / 2;

    // workspace layout (floats): deg[n] | xw1[n*HID] | agg1[n*HID]   (~51.6 MB)
    float* deg  = (float*)d_ws;
    float* xw1  = deg + n;
    float* agg1 = xw1 + (size_t)n * HID;
    float* h2   = xw1;  // xw1 dead after scatter64; reuse for h2 [n*NC]

    hipMemsetAsync(deg, 0, (size_t)n * sizeof(float), stream);
    hipMemsetAsync(agg1, 0, (size_t)n * HID * sizeof(float), stream);

    k_degree<<<(E + 255) / 256, 256, 0, stream>>>(ei + E, E, n, deg);
    k_dinv<<<(n + 255) / 256, 256, 0, stream>>>(deg, n);
    k_xw1<<<(n + 3) / 4, 256, 0, stream>>>(x, W1, xw1, n);

    long long tot1 = (long long)E * 16;
    k_scatter64<<<(unsigned)((tot1 + 255) / 256), 256, 0, stream>>>(ei, E, n, deg, xw1, agg1);

    k_h2<<<(n + 7) / 8, 256, 0, stream>>>(agg1, W2, b1, h2, n);

    long long totOut = (long long)n * NC;
    k_init_out<<<(unsigned)((totOut + 255) / 256), 256, 0, stream>>>(out, b2, totOut);

    long long tot2 = (long long)E * 8;
    k_scatter32<<<(unsigned)((tot2 + 255) / 256), 256, 0, stream>>>(ei, E, n, deg, h2, out);
}

// Round 3
// 711.903 us; speedup vs baseline: 5.7300x; 5.7300x over previous
//
#include <hip/hip_runtime.h>

static constexpr int INF = 16;
static constexpr int HID = 64;
static constexpr int NC  = 32;
static constexpr int SCAN_NB = 128;

__device__ __forceinline__ int clampi(int v, int n) {
    return v < 0 ? 0 : (v >= n ? n - 1 : v);
}

// ---- integer degree histogram over targets ----
__global__ __launch_bounds__(256) void k_count(const int* __restrict__ col, int E, int n,
                                               int* __restrict__ deg) {
    int i = blockIdx.x * 256 + threadIdx.x;
    if (i < E) atomicAdd(deg + clampi(col[i], n), 1);
}

// ---- dinv = deg>0 ? rsqrt(deg) : 0 ----
__global__ __launch_bounds__(256) void k_dinv(const int* __restrict__ deg,
                                              float* __restrict__ dinv, int n) {
    int i = blockIdx.x * 256 + threadIdx.x;
    if (i < n) {
        int d = deg[i];
        dinv[i] = (d > 0) ? rsqrtf((float)d) : 0.0f;
    }
}

// ---- scan phase A: per-block sums ----
__global__ __launch_bounds__(256) void k_scanA(const int* __restrict__ deg, int n, int items,
                                               int* __restrict__ bsum) {
    __shared__ int sh[256];
    int t = threadIdx.x;
    long long g  = (long long)blockIdx.x * 256 + t;
    long long lo = g * items, hi = lo + items;
    if (lo > n) lo = n;
    if (hi > n) hi = n;
    int s = 0;
    for (long long i = lo; i < hi; ++i) s += deg[i];
    sh[t] = s;
    __syncthreads();
    for (int off = 128; off > 0; off >>= 1) {
        if (t < off) sh[t] += sh[t + off];
        __syncthreads();
    }
    if (t == 0) bsum[blockIdx.x] = sh[0];
}

// ---- scan phase B: exclusive scan of block sums (single block) ----
__global__ __launch_bounds__(256) void k_scanB(int* __restrict__ bsum, int nb) {
    __shared__ int sh[256];
    int t = threadIdx.x;
    int v = (t < nb) ? bsum[t] : 0;
    sh[t] = v;
    __syncthreads();
    for (int off = 1; off < 256; off <<= 1) {
        int a = (t >= off) ? sh[t - off] : 0;
        __syncthreads();
        sh[t] += a;
        __syncthreads();
    }
    if (t < nb) bsum[t] = sh[t] - v;   // exclusive
}

// ---- scan phase C: write row_ptr + cursor copy ----
__global__ __launch_bounds__(256) void k_scanC(const int* __restrict__ deg, int n, int items,
                                               const int* __restrict__ bsum, int E,
                                               int* __restrict__ row_ptr, int* __restrict__ cur) {
    __shared__ int sh[256];
    int t = threadIdx.x;
    long long g  = (long long)blockIdx.x * 256 + t;
    long long lo = g * items, hi = lo + items;
    if (lo > n) lo = n;
    if (hi > n) hi = n;
    int s = 0;
    for (long long i = lo; i < hi; ++i) s += deg[i];
    int own = s;
    sh[t] = s;
    __syncthreads();
    for (int off = 1; off < 256; off <<= 1) {
        int a = (t >= off) ? sh[t - off] : 0;
        __syncthreads();
        sh[t] += a;
        __syncthreads();
    }
    int run = bsum[blockIdx.x] + (sh[t] - own);
    for (long long i = lo; i < hi; ++i) {
        row_ptr[i] = run;
        cur[i]     = run;
        run += deg[i];
    }
    if (lo < n && hi == n) row_ptr[n] = E;
}

// ---- CSR fill: bucket source ids by target ----
__global__ __launch_bounds__(256) void k_fill(const int* __restrict__ ei, int E, int n,
                                              int* __restrict__ cur, int* __restrict__ src) {
    int e = blockIdx.x * 256 + threadIdx.x;
    if (e >= E) return;
    int r = clampi(ei[e], n);
    int c = clampi(ei[E + e], n);
    int p = atomicAdd(cur + c, 1);
    src[p] = r;
}

// ---- layer-1 gather-aggregate in INPUT space: xa[v] = dinv[v]*sum x[s]*dinv[s] ----
// 16 threads/node, 16 nodes/block
__global__ __launch_bounds__(256) void k_aggX(const int* __restrict__ ptr,
                                              const int* __restrict__ src,
                                              const float* __restrict__ dinv,
                                              const float* __restrict__ x,
                                              float* __restrict__ xa, int n) {
    int t = threadIdx.x;
    int v = blockIdx.x * 16 + (t >> 4);
    int f = t & 15;
    if (v >= n) return;
    int b = ptr[v], e = ptr[v + 1];
    float acc = 0.0f;
    for (int i = b; i < e; ++i) {
        int s = src[i];
        acc = fmaf(x[(long long)s * INF + f], dinv[s], acc);
    }
    xa[(long long)v * INF + f] = acc * dinv[v];
}

// ---- fused MLP: h2 = relu(xa@W1 + b1) @ W2 ; 16 nodes/block ----
__global__ __launch_bounds__(256) void k_mlp(const float* __restrict__ xa,
                                             const float* __restrict__ W1,
                                             const float* __restrict__ b1,
                                             const float* __restrict__ W2,
                                             float* __restrict__ h2, int n) {
    __shared__ float W1l[INF * HID];   // 4 KB
    __shared__ float W2l[HID * NC];    // 8 KB
    __shared__ float b1l[HID];
    __shared__ float xal[16 * INF];    // 1 KB
    __shared__ float hl[16 * HID];     // 4 KB
    int t = threadIdx.x;
    for (int i = t; i < INF * HID; i += 256) W1l[i] = W1[i];
    for (int i = t; i < HID * NC; i += 256) W2l[i] = W2[i];
    if (t < HID) b1l[t] = b1[t];
    int base = blockIdx.x * 16;
    for (int i = t; i < 16 * INF; i += 256) {
        int r = i >> 4, k = i & 15;
        int v = base + r;
        xal[i] = (v < n) ? xa[(long long)v * INF + k] : 0.0f;
    }
    __syncthreads();
    for (int i = t; i < 16 * HID; i += 256) {
        int r = i >> 6, c = i & 63;
        float s = b1l[c];
#pragma unroll
        for (int k = 0; k < INF; ++k) s = fmaf(xal[r * INF + k], W1l[k * HID + c], s);
        hl[i] = fmaxf(s, 0.0f);
    }
    __syncthreads();
    for (int i = t; i < 16 * NC; i += 256) {
        int r = i >> 5, c = i & 31;
        int v = base + r;
        if (v < n) {
            float s = 0.0f;
#pragma unroll
            for (int k = 0; k < HID; ++k) s = fmaf(hl[r * HID + k], W2l[k * NC + c], s);
            h2[(long long)v * NC + c] = s;
        }
    }
}

// ---- layer-2 gather-aggregate: out[v] = b2 + dinv[v]*sum h2[s]*dinv[s] ----
// 32 threads/node, 8 nodes/block
__global__ __launch_bounds__(256) void k_agg2(const int* __restrict__ ptr,
                                              const int* __restrict__ src,
                                              const float* __restrict__ dinv,
                                              const float* __restrict__ h2,
                                              const float* __restrict__ b2,
                                              float* __restrict__ out, int n) {
    int t = threadIdx.x;
    int v = blockIdx.x * 8 + (t >> 5);
    int f = t & 31;
    if (v >= n) return;
    int b = ptr[v], e = ptr[v + 1];
    float acc = 0.0f;
    for (int i = b; i < e; ++i) {
        int s = src[i];
        acc = fmaf(h2[(long long)s * NC + f], dinv[s], acc);
    }
    out[(long long)v * NC + f] = b2[f] + acc * dinv[v];
}

extern "C" void kernel_launch(void* const* d_in, const int* in_sizes, int n_in,
                              void* d_out, int out_size, void* d_ws, size_t ws_size,
                              hipStream_t stream) {
    const float* x  = (const float*)d_in[0];
    const int*   ei = (const int*)d_in[1];   // int64 in reference -> pushed as int32
    const float* W1 = (const float*)d_in[2];
    const float* b1 = (const float*)d_in[3];
    const float* W2 = (const float*)d_in[4];
    const float* b2 = (const float*)d_in[5];
    float* out = (float*)d_out;

    const int n = in_sizes[0] / INF;
    const int E = in_sizes[1] / 2;

    // ws layout (4B elems): deg_i[n] | row_ptr[n+1] | cur[n] | bsum[128] | src[E] |
    //                       dinv[n] | xa[n*16] | h2[n*32]   (~33.7 MB)
    int*   deg_i   = (int*)d_ws;
    int*   row_ptr = deg_i + n;
    int*   cur     = row_ptr + (n + 1);
    int*   bsum    = cur + n;
    int*   src     = bsum + SCAN_NB;
    float* dinv    = (float*)(src + E);
    float* xa      = dinv + n;
    float* h2      = xa + (size_t)n * INF;

    hipMemsetAsync(deg_i, 0, (size_t)n * sizeof(int), stream);

    k_count<<<(E + 255) / 256, 256, 0, stream>>>(ei + E, E, n, deg_i);
    k_dinv<<<(n + 255) / 256, 256, 0, stream>>>(deg_i, dinv, n);

    int items = (n + SCAN_NB * 256 - 1) / (SCAN_NB * 256);
    k_scanA<<<SCAN_NB, 256, 0, stream>>>(deg_i, n, items, bsum);
    k_scanB<<<1, 256, 0, stream>>>(bsum, SCAN_NB);
    k_scanC<<<SCAN_NB, 256, 0, stream>>>(deg_i, n, items, bsum, E, row_ptr, cur);

    k_fill<<<(E + 255) / 256, 256, 0, stream>>>(ei, E, n, cur, src);

    k_aggX<<<(n + 15) / 16, 256, 0, stream>>>(row_ptr, src, dinv, x, xa, n);
    k_mlp<<<(n + 15) / 16, 256, 0, stream>>>(xa, W1, b1, W2, h2, n);
    k_agg2<<<(n + 7) / 8, 256, 0, stream>>>(row_ptr, src, dinv, h2, b2, out, n);
}

// Round 4
// 397.813 us; speedup vs baseline: 10.2540x; 1.7895x over previous
//
#include <hip/hip_runtime.h>

static constexpr int INF = 16;
static constexpr int HID = 64;
static constexpr int NC  = 32;
static constexpr int SHIFT = 9;      // bucket = target >> 9 (512 nodes/bucket)
static constexpr int BK    = 512;    // nodes per bucket
static constexpr int NBMAX = 256;    // max buckets (n <= 128k)
static constexpr int SPLIT_IT = 16;  // edges per thread in k_split

__device__ __forceinline__ int clampi(int v, int n) {
    return v < 0 ? 0 : (v >= n ? n - 1 : v);
}

// ---- coarse histogram over target buckets (LDS-aggregated) ----
__global__ __launch_bounds__(256) void k_hist1(const int* __restrict__ col, int E, int n,
                                               int* __restrict__ bcnt) {
    __shared__ int h[NBMAX];
    int t = threadIdx.x;
    for (int i = t; i < NBMAX; i += 256) h[i] = 0;
    __syncthreads();
    for (long long e = (long long)blockIdx.x * 256 + t; e < E; e += (long long)gridDim.x * 256)
        atomicAdd(&h[clampi(col[e], n) >> SHIFT], 1);
    __syncthreads();
    for (int i = t; i < NBMAX; i += 256)
        if (h[i]) atomicAdd(bcnt + i, h[i]);
}

// ---- exclusive scan of bucket counts (single block) ----
__global__ __launch_bounds__(256) void k_bscan(const int* __restrict__ bcnt,
                                               int* __restrict__ boff, int* __restrict__ bcur) {
    __shared__ int sh[256];
    int t = threadIdx.x;
    int v = bcnt[t];
    sh[t] = v;
    __syncthreads();
    for (int off = 1; off < 256; off <<= 1) {
        int a = (t >= off) ? sh[t - off] : 0;
        __syncthreads();
        sh[t] += a;
        __syncthreads();
    }
    int ex = sh[t] - v;
    boff[t] = ex;
    bcur[t] = ex;
    if (t == 255) boff[256] = sh[t];
}

// ---- multisplit: partition (src,dst) pairs into coarse bucket regions ----
// one global atomic per (block,bucket); writes in contiguous per-bucket chunks
__global__ __launch_bounds__(256) void k_split(const int* __restrict__ ei, int E, int n,
                                               int* __restrict__ bcur, int2* __restrict__ pairs) {
    __shared__ int lh[NBMAX];    // local histogram, then local cursor
    __shared__ int base[NBMAX];  // global base per bucket for this block
    int t = threadIdx.x;
    long long start = (long long)blockIdx.x * 256 * SPLIT_IT;
    int r[SPLIT_IT], c[SPLIT_IT];
    lh[t] = 0;
    __syncthreads();
#pragma unroll
    for (int i = 0; i < SPLIT_IT; ++i) {
        long long e = start + (long long)i * 256 + t;   // coalesced per i
        if (e < E) {
            r[i] = clampi(ei[e], n);
            c[i] = clampi(ei[E + e], n);
            atomicAdd(&lh[c[i] >> SHIFT], 1);
        } else {
            c[i] = -1;
        }
    }
    __syncthreads();
    {
        int cnt = lh[t];
        base[t] = cnt ? atomicAdd(bcur + t, cnt) : 0;
        lh[t] = 0;   // same-thread index: no cross-thread hazard
    }
    __syncthreads();
#pragma unroll
    for (int i = 0; i < SPLIT_IT; ++i) {
        if (c[i] >= 0) {
            int b = c[i] >> SHIFT;
            int pos = base[b] + atomicAdd(&lh[b], 1);
            pairs[pos] = make_int2(r[i], c[i]);
        }
    }
}

// ---- fine pass: per-bucket deg/dinv/row_ptr + CSR src fill (block-private region) ----
__global__ __launch_bounds__(256) void k_fine(const int2* __restrict__ pairs,
                                              const int* __restrict__ boff,
                                              int n, int E, int NB,
                                              float* __restrict__ dinv,
                                              int* __restrict__ row_ptr,
                                              int* __restrict__ src) {
    __shared__ int h[BK];    // histogram, later cursors
    __shared__ int ex[BK];   // exclusive scan
    __shared__ int sh[256];
    int b = blockIdx.x, t = threadIdx.x;
    int bb = boff[b], be = boff[b + 1];
    h[t] = 0; h[t + 256] = 0;
    __syncthreads();
    for (int i = bb + t; i < be; i += 256)
        atomicAdd(&h[pairs[i].y & (BK - 1)], 1);
    __syncthreads();
    // exclusive scan of 512 bins with 256 threads (pairwise + Hillis-Steele)
    int a0 = h[2 * t], a1 = h[2 * t + 1];
    int ps = a0 + a1;
    sh[t] = ps;
    __syncthreads();
    for (int off = 1; off < 256; off <<= 1) {
        int a = (t >= off) ? sh[t - off] : 0;
        __syncthreads();
        sh[t] += a;
        __syncthreads();
    }
    int ep = sh[t] - ps;
    ex[2 * t] = ep;
    ex[2 * t + 1] = ep + a0;
    __syncthreads();
    // write deg-derived outputs, coalesced
    for (int j = t; j < BK; j += 256) {
        int v = b * BK + j;
        if (v < n) {
            int d = h[j];
            dinv[v] = (d > 0) ? rsqrtf((float)d) : 0.0f;
            row_ptr[v] = bb + ex[j];
        }
    }
    if (b == NB - 1 && t == 0) row_ptr[n] = E;
    // cursors (same-thread index set as the h[j] reads above)
    for (int j = t; j < BK; j += 256) h[j] = bb + ex[j];
    __syncthreads();
    for (int i = bb + t; i < be; i += 256) {
        int2 p = pairs[i];
        int pos = atomicAdd(&h[p.y & (BK - 1)], 1);
        src[pos] = p.x;
    }
}

// ---- layer-1 gather-aggregate in INPUT space: xa[v] = dinv[v]*sum x[s]*dinv[s] ----
__global__ __launch_bounds__(256) void k_aggX(const int* __restrict__ ptr,
                                              const int* __restrict__ src,
                                              const float* __restrict__ dinv,
                                              const float* __restrict__ x,
                                              float* __restrict__ xa, int n) {
    int t = threadIdx.x;
    int v = blockIdx.x * 16 + (t >> 4);
    int f = t & 15;
    if (v >= n) return;
    int b = ptr[v], e = ptr[v + 1];
    float acc = 0.0f;
    for (int i = b; i < e; ++i) {
        int s = src[i];
        acc = fmaf(x[(long long)s * INF + f], dinv[s], acc);
    }
    xa[(long long)v * INF + f] = acc * dinv[v];
}

// ---- fused MLP: h2 = relu(xa@W1 + b1) @ W2 ; 16 nodes/block ----
__global__ __launch_bounds__(256) void k_mlp(const float* __restrict__ xa,
                                             const float* __restrict__ W1,
                                             const float* __restrict__ b1,
                                             const float* __restrict__ W2,
                                             float* __restrict__ h2, int n) {
    __shared__ float W1l[INF * HID];
    __shared__ float W2l[HID * NC];
    __shared__ float b1l[HID];
    __shared__ float xal[16 * INF];
    __shared__ float hl[16 * HID];
    int t = threadIdx.x;
    for (int i = t; i < INF * HID; i += 256) W1l[i] = W1[i];
    for (int i = t; i < HID * NC; i += 256) W2l[i] = W2[i];
    if (t < HID) b1l[t] = b1[t];
    int base = blockIdx.x * 16;
    for (int i = t; i < 16 * INF; i += 256) {
        int r = i >> 4, k = i & 15;
        int v = base + r;
        xal[i] = (v < n) ? xa[(long long)v * INF + k] : 0.0f;
    }
    __syncthreads();
    for (int i = t; i < 16 * HID; i += 256) {
        int r = i >> 6, c = i & 63;
        float s = b1l[c];
#pragma unroll
        for (int k = 0; k < INF; ++k) s = fmaf(xal[r * INF + k], W1l[k * HID + c], s);
        hl[i] = fmaxf(s, 0.0f);
    }
    __syncthreads();
    for (int i = t; i < 16 * NC; i += 256) {
        int r = i >> 5, c = i & 31;
        int v = base + r;
        if (v < n) {
            float s = 0.0f;
#pragma unroll
            for (int k = 0; k < HID; ++k) s = fmaf(hl[r * HID + k], W2l[k * NC + c], s);
            h2[(long long)v * NC + c] = s;
        }
    }
}

// ---- layer-2 gather-aggregate: out[v] = b2 + dinv[v]*sum h2[s]*dinv[s] ----
__global__ __launch_bounds__(256) void k_agg2(const int* __restrict__ ptr,
                                              const int* __restrict__ src,
                                              const float* __restrict__ dinv,
                                              const float* __restrict__ h2,
                                              const float* __restrict__ b2,
                                              float* __restrict__ out, int n) {
    int t = threadIdx.x;
    int v = blockIdx.x * 8 + (t >> 5);
    int f = t & 31;
    if (v >= n) return;
    int b = ptr[v], e = ptr[v + 1];
    float acc = 0.0f;
    for (int i = b; i < e; ++i) {
        int s = src[i];
        acc = fmaf(h2[(long long)s * NC + f], dinv[s], acc);
    }
    out[(long long)v * NC + f] = b2[f] + acc * dinv[v];
}

extern "C" void kernel_launch(void* const* d_in, const int* in_sizes, int n_in,
                              void* d_out, int out_size, void* d_ws, size_t ws_size,
                              hipStream_t stream) {
    const float* x  = (const float*)d_in[0];
    const int*   ei = (const int*)d_in[1];   // int64 in reference -> pushed as int32
    const float* W1 = (const float*)d_in[2];
    const float* b1 = (const float*)d_in[3];
    const float* W2 = (const float*)d_in[4];
    const float* b2 = (const float*)d_in[5];
    float* out = (float*)d_out;

    const int n = in_sizes[0] / INF;
    const int E = in_sizes[1] / 2;
    const int NB = (n + BK - 1) / BK;        // 196 for n=100k (<= NBMAX)

    // ws layout (4B units):
    //   pairs[2E] | src[E] | dinv[n] | row_ptr[n+1] | bcnt[256] | boff[257] | bcur[256]
    // xa[n*16] and h2[n*32] ALIAS the pairs region (pairs dead after k_fine;
    // n*48 ints <= 2E ints).  Total ~39 MB.
    int2*  pairs   = (int2*)d_ws;
    int*   src     = (int*)d_ws + 2 * (size_t)E;
    float* dinv    = (float*)(src + E);
    int*   row_ptr = (int*)(dinv + n);
    int*   bcnt    = row_ptr + (n + 1);
    int*   boff    = bcnt + NBMAX;
    int*   bcur    = boff + (NBMAX + 1);
    float* xa      = (float*)d_ws;           // aliases pairs
    float* h2      = xa + (size_t)n * INF;   // aliases pairs

    hipMemsetAsync(bcnt, 0, NBMAX * sizeof(int), stream);

    k_hist1<<<512, 256, 0, stream>>>(ei + E, E, n, bcnt);
    k_bscan<<<1, 256, 0, stream>>>(bcnt, boff, bcur);

    int splitBlocks = (int)((E + 256LL * SPLIT_IT - 1) / (256LL * SPLIT_IT));
    k_split<<<splitBlocks, 256, 0, stream>>>(ei, E, n, bcur, pairs);

    k_fine<<<NB, 256, 0, stream>>>(pairs, boff, n, E, NB, dinv, row_ptr, src);

    k_aggX<<<(n + 15) / 16, 256, 0, stream>>>(row_ptr, src, dinv, x, xa, n);
    k_mlp<<<(n + 15) / 16, 256, 0, stream>>>(xa, W1, b1, W2, h2, n);
    k_agg2<<<(n + 7) / 8, 256, 0, stream>>>(row_ptr, src, dinv, h2, b2, out, n);
}

// Round 5
// 254.327 us; speedup vs baseline: 16.0391x; 1.5642x over previous
//
#include <hip/hip_runtime.h>
#include <hip/hip_fp16.h>

static constexpr int INF = 16;
static constexpr int HID = 64;
static constexpr int NC  = 32;
static constexpr int SHIFT = 9;      // bucket = target >> 9 (512 nodes/bucket)
static constexpr int BK    = 512;    // nodes per bucket
static constexpr int NBMAX = 256;    // max buckets (n <= 128k)
static constexpr int SPLIT_IT = 32;  // edges per thread in k_split

struct alignas(8) half4 { __half2 lo, hi; };

__device__ __forceinline__ int clampi(int v, int n) {
    return v < 0 ? 0 : (v >= n ? n - 1 : v);
}

// ---- coarse histogram over target buckets (LDS-aggregated) ----
__global__ __launch_bounds__(256) void k_hist1(const int* __restrict__ col, int E, int n,
                                               int* __restrict__ bcnt) {
    __shared__ int h[NBMAX];
    int t = threadIdx.x;
    for (int i = t; i < NBMAX; i += 256) h[i] = 0;
    __syncthreads();
    for (long long e = (long long)blockIdx.x * 256 + t; e < E; e += (long long)gridDim.x * 256)
        atomicAdd(&h[clampi(col[e], n) >> SHIFT], 1);
    __syncthreads();
    for (int i = t; i < NBMAX; i += 256)
        if (h[i]) atomicAdd(bcnt + i, h[i]);
}

// ---- exclusive scan of bucket counts (single block) ----
__global__ __launch_bounds__(256) void k_bscan(const int* __restrict__ bcnt,
                                               int* __restrict__ boff, int* __restrict__ bcur) {
    __shared__ int sh[256];
    int t = threadIdx.x;
    int v = bcnt[t];
    sh[t] = v;
    __syncthreads();
    for (int off = 1; off < 256; off <<= 1) {
        int a = (t >= off) ? sh[t - off] : 0;
        __syncthreads();
        sh[t] += a;
        __syncthreads();
    }
    int ex = sh[t] - v;
    boff[t] = ex;
    bcur[t] = ex;
    if (t == 255) boff[256] = sh[t];
}

// ---- multisplit: partition (src,dst) pairs into coarse bucket regions ----
__global__ __launch_bounds__(256) void k_split(const int* __restrict__ ei, int E, int n,
                                               int* __restrict__ bcur, int2* __restrict__ pairs) {
    __shared__ int lh[NBMAX];
    __shared__ int base[NBMAX];
    int t = threadIdx.x;
    long long start = (long long)blockIdx.x * 256 * SPLIT_IT;
    int r[SPLIT_IT], c[SPLIT_IT];
    lh[t] = 0;
    __syncthreads();
#pragma unroll
    for (int i = 0; i < SPLIT_IT; ++i) {
        long long e = start + (long long)i * 256 + t;   // coalesced per i
        if (e < E) {
            r[i] = clampi(ei[e], n);
            c[i] = clampi(ei[E + e], n);
            atomicAdd(&lh[c[i] >> SHIFT], 1);
        } else {
            c[i] = -1;
        }
    }
    __syncthreads();
    {
        int cnt = lh[t];
        base[t] = cnt ? atomicAdd(bcur + t, cnt) : 0;
        lh[t] = 0;
    }
    __syncthreads();
#pragma unroll
    for (int i = 0; i < SPLIT_IT; ++i) {
        if (c[i] >= 0) {
            int b = c[i] >> SHIFT;
            int pos = base[b] + atomicAdd(&lh[b], 1);
            pairs[pos] = make_int2(r[i], c[i]);
        }
    }
}

// ---- fine pass: per-bucket deg/dinv/row_ptr + CSR src fill ----
__global__ __launch_bounds__(256) void k_fine(const int2* __restrict__ pairs,
                                              const int* __restrict__ boff,
                                              int n, int E, int NB,
                                              float* __restrict__ dinv,
                                              int* __restrict__ row_ptr,
                                              int* __restrict__ src) {
    __shared__ int h[BK];
    __shared__ int ex[BK];
    __shared__ int sh[256];
    int b = blockIdx.x, t = threadIdx.x;
    int bb = boff[b], be = boff[b + 1];
    h[t] = 0; h[t + 256] = 0;
    __syncthreads();
    for (int i = bb + t; i < be; i += 256)
        atomicAdd(&h[pairs[i].y & (BK - 1)], 1);
    __syncthreads();
    int a0 = h[2 * t], a1 = h[2 * t + 1];
    int ps = a0 + a1;
    sh[t] = ps;
    __syncthreads();
    for (int off = 1; off < 256; off <<= 1) {
        int a = (t >= off) ? sh[t - off] : 0;
        __syncthreads();
        sh[t] += a;
        __syncthreads();
    }
    int ep = sh[t] - ps;
    ex[2 * t] = ep;
    ex[2 * t + 1] = ep + a0;
    __syncthreads();
    for (int j = t; j < BK; j += 256) {
        int v = b * BK + j;
        if (v < n) {
            int d = h[j];
            dinv[v] = (d > 0) ? rsqrtf((float)d) : 0.0f;
            row_ptr[v] = bb + ex[j];
        }
    }
    if (b == NB - 1 && t == 0) row_ptr[n] = E;
    for (int j = t; j < BK; j += 256) h[j] = bb + ex[j];
    __syncthreads();
    for (int i = bb + t; i < be; i += 256) {
        int2 p = pairs[i];
        int pos = atomicAdd(&h[p.y & (BK - 1)], 1);
        src[pos] = p.x;
    }
}

// ---- cast + pre-scale: xs[v] = fp16(x[v] * dinv[v]) ; one node/thread ----
__global__ __launch_bounds__(256) void k_xcast(const float* __restrict__ x,
                                               const float* __restrict__ dinv,
                                               __half2* __restrict__ xs, int n) {
    int v = blockIdx.x * 256 + threadIdx.x;
    if (v >= n) return;
    float dv = dinv[v];
    const float* xr = x + (long long)v * INF;
    __half2* xo = xs + (long long)v * (INF / 2);
#pragma unroll
    for (int k = 0; k < INF / 2; ++k)
        xo[k] = __floats2half2_rn(xr[2 * k] * dv, xr[2 * k + 1] * dv);
}

// ---- layer-1 gather: xa[v] = dinv[v] * sum xs[src] ; 4 lanes/node, fp32 accum ----
__global__ __launch_bounds__(256) void k_aggX(const int* __restrict__ ptr,
                                              const int* __restrict__ src,
                                              const float* __restrict__ dinv,
                                              const __half* __restrict__ xs,
                                              float* __restrict__ xa, int n) {
    int t = threadIdx.x;
    int v = blockIdx.x * 64 + (t >> 2);
    int lane = t & 3;
    if (v >= n) return;
    int b = ptr[v], e = ptr[v + 1];
    float a0 = 0.f, a1 = 0.f, a2 = 0.f, a3 = 0.f;
    for (int i = b; i < e; ++i) {
        int s = src[i];
        half4 hv = *reinterpret_cast<const half4*>(xs + (long long)s * INF + lane * 4);
        float2 f0 = __half22float2(hv.lo);
        float2 f1 = __half22float2(hv.hi);
        a0 += f0.x; a1 += f0.y; a2 += f1.x; a3 += f1.y;
    }
    float dv = dinv[v];
    float4 o = make_float4(a0 * dv, a1 * dv, a2 * dv, a3 * dv);
    *reinterpret_cast<float4*>(xa + (long long)v * INF + lane * 4) = o;
}

// ---- fused MLP: h2h = fp16( (relu(xa@W1+b1)@W2) * dinv[v] ) ; 16 nodes/block ----
__global__ __launch_bounds__(256) void k_mlp(const float* __restrict__ xa,
                                             const float* __restrict__ W1,
                                             const float* __restrict__ b1,
                                             const float* __restrict__ W2,
                                             const float* __restrict__ dinv,
                                             __half2* __restrict__ h2h, int n) {
    __shared__ float W1l[INF * HID];
    __shared__ float W2l[HID * NC];
    __shared__ float b1l[HID];
    __shared__ float xal[16 * INF];
    __shared__ float hl[16 * HID];
    int t = threadIdx.x;
    for (int i = t; i < INF * HID; i += 256) W1l[i] = W1[i];
    for (int i = t; i < HID * NC; i += 256) W2l[i] = W2[i];
    if (t < HID) b1l[t] = b1[t];
    int base = blockIdx.x * 16;
    for (int i = t; i < 16 * INF; i += 256) {
        int r = i >> 4, k = i & 15;
        int v = base + r;
        xal[i] = (v < n) ? xa[(long long)v * INF + k] : 0.0f;
    }
    __syncthreads();
    for (int i = t; i < 16 * HID; i += 256) {
        int r = i >> 6, c = i & 63;
        float s = b1l[c];
#pragma unroll
        for (int k = 0; k < INF; ++k) s = fmaf(xal[r * INF + k], W1l[k * HID + c], s);
        hl[i] = fmaxf(s, 0.0f);
    }
    __syncthreads();
    // 16 nodes x 16 half2-pairs = 256 -> one pair per thread
    {
        int r = t >> 4, cp = t & 15;
        int v = base + r;
        if (v < n) {
            int c0 = 2 * cp;
            float s0 = 0.f, s1 = 0.f;
#pragma unroll
            for (int k = 0; k < HID; ++k) {
                float hv = hl[r * HID + k];
                s0 = fmaf(hv, W2l[k * NC + c0], s0);
                s1 = fmaf(hv, W2l[k * NC + c0 + 1], s1);
            }
            float dv = dinv[v];
            h2h[(long long)v * (NC / 2) + cp] = __floats2half2_rn(s0 * dv, s1 * dv);
        }
    }
}

// ---- layer-2 gather: out[v] = b2 + dinv[v] * sum h2h[src] ; 8 lanes/node ----
__global__ __launch_bounds__(256) void k_agg2(const int* __restrict__ ptr,
                                              const int* __restrict__ src,
                                              const float* __restrict__ dinv,
                                              const __half* __restrict__ h2h,
                                              const float* __restrict__ b2,
                                              float* __restrict__ out, int n) {
    int t = threadIdx.x;
    int v = blockIdx.x * 32 + (t >> 3);
    int lane = t & 7;
    if (v >= n) return;
    int b = ptr[v], e = ptr[v + 1];
    float a0 = 0.f, a1 = 0.f, a2 = 0.f, a3 = 0.f;
    for (int i = b; i < e; ++i) {
        int s = src[i];
        half4 hv = *reinterpret_cast<const half4*>(h2h + (long long)s * NC + lane * 4);
        float2 f0 = __half22float2(hv.lo);
        float2 f1 = __half22float2(hv.hi);
        a0 += f0.x; a1 += f0.y; a2 += f1.x; a3 += f1.y;
    }
    float dv = dinv[v];
    const float4 bb = *reinterpret_cast<const float4*>(b2 + lane * 4);
    float4 o = make_float4(fmaf(a0, dv, bb.x), fmaf(a1, dv, bb.y),
                           fmaf(a2, dv, bb.z), fmaf(a3, dv, bb.w));
    *reinterpret_cast<float4*>(out + (long long)v * NC + lane * 4) = o;
}

extern "C" void kernel_launch(void* const* d_in, const int* in_sizes, int n_in,
                              void* d_out, int out_size, void* d_ws, size_t ws_size,
                              hipStream_t stream) {
    const float* x  = (const float*)d_in[0];
    const int*   ei = (const int*)d_in[1];   // int64 in reference -> pushed as int32
    const float* W1 = (const float*)d_in[2];
    const float* b1 = (const float*)d_in[3];
    const float* W2 = (const float*)d_in[4];
    const float* b2 = (const float*)d_in[5];
    float* out = (float*)d_out;

    const int n = in_sizes[0] / INF;
    const int E = in_sizes[1] / 2;
    const int NB = (n + BK - 1) / BK;        // 196 for n=100k

    // ws layout (4B units):
    //   pairs[2E] | src[E] | dinv[n] | row_ptr[n+1] | bcnt | boff | bcur
    // After k_fine, pairs region is reused: xs[8n ints] | xa[16n] | h2h[16n]
    //   (40n ints = 16 MB <= 2E ints = 25.6 MB)
    int*    wsi     = (int*)d_ws;
    int2*   pairs   = (int2*)d_ws;
    int*    src     = wsi + 2 * (size_t)E;
    float*  dinv    = (float*)(src + E);
    int*    row_ptr = (int*)(dinv + n);
    int*    bcnt    = row_ptr + (n + 1);
    int*    boff    = bcnt + NBMAX;
    int*    bcur    = boff + (NBMAX + 1);
    __half* xs      = (__half*)d_ws;                       // aliases pairs
    float*  xa      = (float*)(wsi + (size_t)8 * n);       // aliases pairs
    __half* h2h     = (__half*)(wsi + (size_t)24 * n);     // aliases pairs

    hipMemsetAsync(bcnt, 0, NBMAX * sizeof(int), stream);

    k_hist1<<<512, 256, 0, stream>>>(ei + E, E, n, bcnt);
    k_bscan<<<1, 256, 0, stream>>>(bcnt, boff, bcur);

    int splitBlocks = (int)((E + 256LL * SPLIT_IT - 1) / (256LL * SPLIT_IT));
    k_split<<<splitBlocks, 256, 0, stream>>>(ei, E, n, bcur, pairs);

    k_fine<<<NB, 256, 0, stream>>>(pairs, boff, n, E, NB, dinv, row_ptr, src);

    k_xcast<<<(n + 255) / 256, 256, 0, stream>>>(x, dinv, (__half2*)xs, n);
    k_aggX<<<(n + 63) / 64, 256, 0, stream>>>(row_ptr, src, dinv, xs, xa, n);
    k_mlp<<<(n + 15) / 16, 256, 0, stream>>>(xa, W1, b1, W2, dinv, (__half2*)h2h, n);
    k_agg2<<<(n + 31) / 32, 256, 0, stream>>>(row_ptr, src, dinv, h2h, b2, out, n);
}